// Round 19
// baseline (180.586 us; speedup 1.0000x reference)
//
#include <hip/hip_runtime.h>

#define EPSF 1e-12f

typedef short bf16x8 __attribute__((ext_vector_type(8)));
typedef float f32x4 __attribute__((ext_vector_type(4)));

__device__ __forceinline__ unsigned short f2bf(float f) {
  unsigned int u = __float_as_uint(f);
  unsigned int r = u + 0x7fffu + ((u >> 16) & 1u);  // RNE
  return (unsigned short)(r >> 16);
}

union SMem {
  struct { float As[64][36]; float Bs[64][36]; } g;            // 18.4 KB
  struct {                                                      // ~42.5 KB
    unsigned short W[128][136];
    int tg[256];
    int maskA[128], maskB[128];
    float Ri[128], Cl[128];
    float SMRAW[16][17], SP[16][17], SQ[16][17];
    float red[256];
    int Plist[16], Qlist[16];
    int ctrP, ctrQ;
  } c;
  struct { float bins[4][33]; int tg[256]; float diag[256]; } s;
  struct { float rl[256]; float rf[256]; } f;
};

// Device-scope spin barrier (residency-by-capacity; 43KB LDS -> 3 blk/CU,
// grid 256 <= 768 capacity, so all blocks are resident -> no deadlock).
__device__ __forceinline__ void garrive(unsigned* ctr, int tid) {
  __syncthreads();
  if (tid == 0) {
    __threadfence();
    atomicAdd(ctr, 1u);
  }
}
__device__ __forceinline__ void gbarrier(unsigned* ctr, unsigned tgt, int tid) {
  __syncthreads();
  if (tid == 0) {
    __threadfence();
    atomicAdd(ctr, 1u);
    while (atomicAdd(ctr, 0u) < tgt) __builtin_amdgcn_s_sleep(1);
    __threadfence();
  }
  __syncthreads();
}

// ---------------------------------------------------------------------------
// MEGAKERNEL: whole pipeline in one dispatch. grid 256 x 256 threads.
//  A) blocks < 16*S : split-K GEMM slice -> Gp            [barrier0: 256]
//  B) blocks < 64   : slice-reduce -> G, accuracy, LSEtab [barrier1: 64]
//  C) blocks < 64   : class loss (MFMA SYRK, r18 body)    [barrier2: 64]
//  D) block 0       : final reduce -> out (f32 loss, correct)
// ---------------------------------------------------------------------------
__global__ __launch_bounds__(256, 2) void TransitionLoss_30666066494151_kernel(
    const float* __restrict__ F, const int* __restrict__ targets,
    unsigned* __restrict__ ctr, float* __restrict__ lsp,
    float* __restrict__ lan, float* __restrict__ cnts,
    float* __restrict__ flags, float* __restrict__ LSEtab,
    float* __restrict__ G, float* __restrict__ Gp,
    float* __restrict__ out, int n, int d, int S) {
  __shared__ SMem sm;
  const int tid = threadIdx.x;
  const int b = blockIdx.x;
  const int nn = n * n;
  const int nhalf = n >> 1;

  // ---------------- Phase A: GEMM slices ----------------
  if (b < 16 * S) {
    const int bx = b & 3, by = (b >> 2) & 3, kz = b >> 4;
    const int kchunk = d / S;
    const int ty = tid >> 4, tx = tid & 15;
    const int lrow = tid >> 2;
    const int lcol = (tid & 3) * 8;
    const float* Ap = F + (size_t)(bx * 64 + lrow) * d + (size_t)kz * kchunk + lcol;
    const float* Bp = F + (size_t)(by * 64 + lrow) * d + (size_t)kz * kchunk + lcol;
    float acc[4][4];
    for (int r = 0; r < 4; r++)
      for (int c = 0; c < 4; c++) acc[r][c] = 0.0f;

    for (int ks = 0; ks < kchunk; ks += 32) {
      float4 a0 = *(const float4*)(Ap + ks);
      float4 a1 = *(const float4*)(Ap + ks + 4);
      float4 b0 = *(const float4*)(Bp + ks);
      float4 b1 = *(const float4*)(Bp + ks + 4);
      __syncthreads();
      *(float4*)&sm.g.As[lrow][lcol]     = a0;
      *(float4*)&sm.g.As[lrow][lcol + 4] = a1;
      *(float4*)&sm.g.Bs[lrow][lcol]     = b0;
      *(float4*)&sm.g.Bs[lrow][lcol + 4] = b1;
      __syncthreads();
#pragma unroll
      for (int kk = 0; kk < 32; kk += 4) {
        float4 av[4], bv[4];
#pragma unroll
        for (int r = 0; r < 4; r++)
          av[r] = *(const float4*)&sm.g.As[ty + 16 * r][kk];
#pragma unroll
        for (int c = 0; c < 4; c++)
          bv[c] = *(const float4*)&sm.g.Bs[tx + 16 * c][kk];
#pragma unroll
        for (int r = 0; r < 4; r++) {
          float4 A = av[r];
#pragma unroll
          for (int c = 0; c < 4; c++) {
            float4 B = bv[c];
            acc[r][c] += A.x * B.x + A.y * B.y + A.z * B.z + A.w * B.w;
          }
        }
      }
    }
    float* Gs = Gp + (size_t)kz * nn;
#pragma unroll
    for (int r = 0; r < 4; r++)
#pragma unroll
      for (int c = 0; c < 4; c++)
        Gs[(size_t)(bx * 64 + ty + 16 * r) * n + (by * 64 + tx + 16 * c)] =
            acc[r][c];
  }

  // barrier 0: all 256 blocks; blocks >= 64 arrive and exit.
  if (b >= 64) { garrive(&ctr[0], tid); return; }
  gbarrier(&ctr[0], 256, tid);

  // ---------------- Phase B: reduce + stats (blocks 0..63) ----------------
  {
    const int lane = tid & 63;
    const int w = tid >> 6;
    sm.s.tg[tid] = targets[tid];
    {
      float s0 = 0.0f;
      for (int s = 0; s < S; s++)
        s0 += Gp[(size_t)s * nn + (size_t)tid * (n + 1)];
      sm.s.diag[tid] = s0;
    }
    if (tid < 128) sm.s.bins[tid >> 5][tid & 31] = 0.0f;
    __syncthreads();

    const int r = b * 4 + w;
    const int opp0 = (r < nhalf) ? nhalf : 0;
    const int myid = sm.s.tg[r];
    const float sqr = sm.s.diag[r];

    float4 v = make_float4(0.f, 0.f, 0.f, 0.f);
    for (int s = 0; s < S; s++) {
      float4 t = *(const float4*)(Gp + (size_t)s * nn + (size_t)r * n + lane * 4);
      v.x += t.x; v.y += t.y; v.z += t.z; v.w += t.w;
    }
    *(float4*)(G + (size_t)r * n + lane * 4) = v;
    float gv[4] = {v.x, v.y, v.z, v.w};

    float dap = -1e30f, dan = 1e30f;
#pragma unroll
    for (int q = 0; q < 4; q++) {
      int j = lane * 4 + q;
      float dist = sqrtf(fmaxf(sqr + sm.s.diag[j] - 2.0f * gv[q], EPSF));
      if (sm.s.tg[j] == myid) dap = fmaxf(dap, dist);
      else                    dan = fminf(dan, dist);
    }
#pragma unroll
    for (int off = 32; off; off >>= 1) {
      dap = fmaxf(dap, __shfl_xor(dap, off));
      dan = fminf(dan, __shfl_xor(dan, off));
    }
    if (lane == 0) flags[r] = (dan >= dap) ? 1.0f : 0.0f;

    float mx = -1e30f;
#pragma unroll
    for (int q = 0; q < 4; q++) {
      int j = lane * 4 + q;
      if (j >= opp0 && j < opp0 + nhalf) mx = fmaxf(mx, gv[q]);
    }
#pragma unroll
    for (int off = 32; off; off >>= 1) mx = fmaxf(mx, __shfl_xor(mx, off));

#pragma unroll
    for (int q = 0; q < 4; q++) {
      int j = lane * 4 + q;
      if (j >= opp0 && j < opp0 + nhalf)
        atomicAdd(&sm.s.bins[w][sm.s.tg[j]], __expf(gv[q] - mx));
    }
    __syncthreads();

    if (lane < 32) {
      float bb = sm.s.bins[w][lane];
      float lv = __shfl_up(bb, 1, 32);
      if (lane == 0) lv = 0.0f;
#pragma unroll
      for (int off = 1; off < 32; off <<= 1) {
        float t = __shfl_up(lv, off, 32);
        if (lane >= off) lv += t;
      }
      float rvv = __shfl_down(bb, 1, 32);
      if (lane == 31) rvv = 0.0f;
#pragma unroll
      for (int off = 1; off < 32; off <<= 1) {
        float t = __shfl_down(rvv, off, 32);
        if (lane + off < 32) rvv += t;
      }
      float excl = fmaxf(lv + rvv, 1e-37f);
      LSEtab[(size_t)lane * n + r] = mx + __logf(excl);  // [id][row]
    }
  }

  gbarrier(&ctr[1], 64, tid);

  // ---------------- Phase C: class loss (blocks 0..63) ----------------
  {
    const int cls = b;
    const int myid = cls & 31;
    const int hA = cls >> 5;
    const int rowA0 = hA * nhalf;
    const int colB0 = nhalf - rowA0;

    sm.c.tg[tid] = targets[tid];
    if (tid == 0) { sm.c.ctrP = 0; sm.c.ctrQ = 0; }
    __syncthreads();

    if (tid < 128) {
      sm.c.maskA[tid] = (sm.c.tg[rowA0 + tid] != myid) ? 1 : 0;
      sm.c.Ri[tid] = LSEtab[(size_t)myid * n + rowA0 + tid];
    } else {
      sm.c.maskB[tid - 128] = (sm.c.tg[colB0 + tid - 128] != myid) ? 1 : 0;
      sm.c.Cl[tid - 128] = LSEtab[(size_t)myid * n + colB0 + tid - 128];
    }
    if (sm.c.tg[tid] == myid) {
      int inAhalf = (((tid >= nhalf) ? 1 : 0) == hA) ? 1 : 0;
      if (inAhalf) { int k = atomicAdd(&sm.c.ctrP, 1); if (k < 16) sm.c.Plist[k] = tid; }
      else         { int k = atomicAdd(&sm.c.ctrQ, 1); if (k < 16) sm.c.Qlist[k] = tid; }
    }
    __syncthreads();
    const int nP = min(sm.c.ctrP, 16), nQ = min(sm.c.ctrQ, 16);

#pragma unroll
    for (int k8 = 0; k8 < 2; k8++) {
      float4 g[8];
#pragma unroll
      for (int u = 0; u < 8; u++) {
        int e4 = tid + 256 * (k8 * 8 + u);
        int i = e4 >> 5;
        int l4 = (e4 & 31) << 2;
        g[u] = *(const float4*)(G + (size_t)(rowA0 + i) * n + colB0 + l4);
      }
#pragma unroll
      for (int u = 0; u < 8; u++) {
        int e4 = tid + 256 * (k8 * 8 + u);
        int i = e4 >> 5;
        int l4 = (e4 & 31) << 2;
        float rih = 0.5f * sm.c.Ri[i];
        int ma = sm.c.maskA[i];
        float w0 = (ma && sm.c.maskB[l4 + 0]) ? __expf(g[u].x - rih - 0.5f * sm.c.Cl[l4 + 0]) : 0.0f;
        float w1 = (ma && sm.c.maskB[l4 + 1]) ? __expf(g[u].y - rih - 0.5f * sm.c.Cl[l4 + 1]) : 0.0f;
        float w2 = (ma && sm.c.maskB[l4 + 2]) ? __expf(g[u].z - rih - 0.5f * sm.c.Cl[l4 + 2]) : 0.0f;
        float w3 = (ma && sm.c.maskB[l4 + 3]) ? __expf(g[u].w - rih - 0.5f * sm.c.Cl[l4 + 3]) : 0.0f;
        uint2 packed;
        packed.x = (unsigned)f2bf(w0) | ((unsigned)f2bf(w1) << 16);
        packed.y = (unsigned)f2bf(w2) | ((unsigned)f2bf(w3) << 16);
        *(uint2*)&sm.c.W[i][l4] = packed;
      }
    }

    {
      int p = tid >> 4, q = tid & 15;
      float v = 0.0f;
      if (p < nP && q < nQ) v = G[(size_t)sm.c.Plist[p] * n + sm.c.Qlist[q]];
      sm.c.SMRAW[p][q] = v;
    }
    __syncthreads();

    const int lane = tid & 63;
    const int wv = tid >> 6;
    const int m16 = lane & 15;
    const int kh = lane >> 4;
    f32x4 acc[2][8];
#pragma unroll
    for (int r = 0; r < 2; r++)
#pragma unroll
      for (int c = 0; c < 8; c++) acc[r][c] = (f32x4){0.f, 0.f, 0.f, 0.f};

#pragma unroll
    for (int kc = 0; kc < 4; kc++) {
      const int koff = kc * 32 + kh * 8;
      bf16x8 bfrag[8];
#pragma unroll
      for (int c = 0; c < 8; c++)
        bfrag[c] = *(const bf16x8*)&sm.c.W[c * 16 + m16][koff];
#pragma unroll
      for (int r = 0; r < 2; r++) {
        bf16x8 afrag = bfrag[wv * 2 + r];
#pragma unroll
        for (int c = 0; c < 8; c++)
          acc[r][c] = __builtin_amdgcn_mfma_f32_16x16x32_bf16(
              afrag, bfrag[c], acc[r][c], 0, 0, 0);
      }
    }

    float lsum = 0.0f;
#pragma unroll
    for (int r = 0; r < 2; r++)
#pragma unroll
      for (int c = 0; c < 8; c++) {
        f32x4 D = acc[r][c];
        int jcol = c * 16 + m16;
        float rj = sm.c.Ri[jcol];
#pragma unroll
        for (int e = 0; e < 4; e++) {
          int irow = wv * 32 + r * 16 + kh * 4 + e;
          float t = __expf(0.5f * (rj - sm.c.Ri[irow])) * D[e];
          lsum += fmaxf(sqrtf(fmaxf(t, EPSF)) - 0.2f, 0.0f);
        }
      }
    sm.c.red[tid] = lsum;
    __syncthreads();
    for (int s2 = 128; s2 > 0; s2 >>= 1) {
      if (tid < s2) sm.c.red[tid] += sm.c.red[tid + s2];
      __syncthreads();
    }
    if (tid == 0) lsp[cls] = sm.c.red[0];

    __syncthreads();
    sm.c.red[tid] = (tid < 128) ? (float)sm.c.maskA[tid] : 0.0f;
    __syncthreads();
    for (int s2 = 128; s2 > 0; s2 >>= 1) {
      if (tid < s2) sm.c.red[tid] += sm.c.red[tid + s2];
      __syncthreads();
    }
    if (tid == 0) { cnts[cls * 2 + 0] = sm.c.red[0]; cnts[cls * 2 + 1] = (float)nP; }

    if (tid < nP) {
      float mx = -1e30f;
      for (int q = 0; q < nQ; q++) mx = fmaxf(mx, sm.c.SMRAW[tid][q]);
      float s = 0.0f;
      for (int q = 0; q < nQ; q++) s += __expf(sm.c.SMRAW[tid][q] - mx);
      for (int q = 0; q < nQ; q++)
        sm.c.SP[tid][q] = __expf(sm.c.SMRAW[tid][q] - mx) / s;
    }
    if (tid >= 64 && tid < 64 + nQ) {
      int q = tid - 64;
      float mx = -1e30f;
      for (int p = 0; p < nP; p++) mx = fmaxf(mx, sm.c.SMRAW[p][q]);
      float s = 0.0f;
      for (int p = 0; p < nP; p++) s += __expf(sm.c.SMRAW[p][q] - mx);
      for (int p = 0; p < nP; p++)
        sm.c.SQ[q][p] = __expf(sm.c.SMRAW[p][q] - mx) / s;
    }
    __syncthreads();
    float lv = 0.0f;
    if (tid < nP * nP) {
      int i = tid / nP, j = tid - i * nP;
      float t = 0.0f;
      for (int l = 0; l < nQ; l++) t += sm.c.SP[i][l] * sm.c.SQ[l][j];
      lv = fmaxf(0.5f - sqrtf(fmaxf(t, EPSF)), 0.0f);
    }
    sm.c.red[tid] = lv;
    __syncthreads();
    for (int s2 = 128; s2 > 0; s2 >>= 1) {
      if (tid < s2) sm.c.red[tid] += sm.c.red[tid + s2];
      __syncthreads();
    }
    if (tid == 0) lan[cls] = sm.c.red[0];
  }

  // barrier 2: blocks 1..63 arrive and exit; block 0 waits.
  if (b != 0) { garrive(&ctr[2], tid); return; }
  gbarrier(&ctr[2], 64, tid);

  // ---------------- Phase D: final reduce (block 0) ----------------
  {
    float lv = 0.0f;
    if (tid < 64) {
      float nA = cnts[tid * 2 + 0];
      float nP = cnts[tid * 2 + 1];
      if (nP > 0.5f && nA > 0.5f)
        lv = nP * (lsp[tid] / (nA * nA) + lan[tid] / (nP * nP));
    }
    sm.f.rl[tid] = lv;
    sm.f.rf[tid] = flags[tid];
    __syncthreads();
    for (int s2 = 128; s2 > 0; s2 >>= 1) {
      if (tid < s2) {
        sm.f.rl[tid] += sm.f.rl[tid + s2];
        sm.f.rf[tid] += sm.f.rf[tid + s2];
      }
      __syncthreads();
    }
    if (tid == 0) {
      out[0] = sm.f.rl[0] / (float)n;
      out[1] = sm.f.rf[0];
    }
  }
}

extern "C" void kernel_launch(void* const* d_in, const int* in_sizes, int n_in,
                              void* d_out, int out_size, void* d_ws,
                              size_t ws_size, hipStream_t stream) {
  const float* feature = (const float*)d_in[0];
  const int* targets = (const int*)d_in[1];
  const int n = in_sizes[1];            // 256
  const int d = in_sizes[0] / n;        // 2048
  const int nn = n * n;
  const size_t smallf = 16 + 64 + 64 + 128 + 256 + (size_t)n * 32;

  int S = 1;
  if (ws_size >= (smallf + nn + (size_t)16 * nn) * sizeof(float)) S = 16;
  else if (ws_size >= (smallf + nn + (size_t)4 * nn) * sizeof(float)) S = 4;

  unsigned* ctr = (unsigned*)d_ws;      // 16 uints (barrier counters)
  float* base = (float*)d_ws + 16;
  float* lsp = base;                    // 64
  float* lan = lsp + 64;                // 64
  float* cnts = lan + 64;               // 128
  float* flags = cnts + 128;            // 256
  float* LSEtab = flags + 256;          // 32*n ([id][row])
  float* G = LSEtab + (size_t)n * 32;   // nn
  float* Gp = (S > 1) ? (G + nn) : G;   // S*nn (alias G when S==1)
  float* out = (float*)d_out;

  hipMemsetAsync(d_ws, 0, 16 * sizeof(unsigned), stream);

  TransitionLoss_30666066494151_kernel<<<256, 256, 0, stream>>>(
      feature, targets, ctr, lsp, lan, cnts, flags, LSEtab, G, Gp, out, n, d, S);
}

// Round 20
// 151.933 us; speedup vs baseline: 1.1886x; 1.1886x over previous
//
#include <hip/hip_runtime.h>

#define EPSF 1e-12f

typedef short bf16x8 __attribute__((ext_vector_type(8)));
typedef float f32x4 __attribute__((ext_vector_type(4)));

__device__ __forceinline__ unsigned short f2bf(float f) {
  unsigned int u = __float_as_uint(f);
  unsigned int r = u + 0x7fffu + ((u >> 16) & 1u);  // RNE
  return (unsigned short)(r >> 16);
}

union SMem {
  struct { float As[64][36]; float Bs[64][36]; } g;            // 18.4 KB
  struct {                                                      // ~42.5 KB
    unsigned short W[128][136];
    int tg[256];
    int maskA[128], maskB[128];
    float Ri[128], Cl[128];
    float SMRAW[16][17], SP[16][17], SQ[16][17];
    float red[256];
    int Plist[16], Qlist[16];
    int ctrP, ctrQ;
  } c;
  struct { float bins[4][33]; int tg[256]; float diag[256]; } s;
  struct { float rl[256]; float rf[256]; } f;
};

// Arrival: workgroup-sync, then tid0 releases + increments (single RMW).
__device__ __forceinline__ void arrive(unsigned* c, int tid) {
  __syncthreads();
  if (tid == 0) {
    __threadfence();
    atomicAdd(c, 1u);
  }
}
// Wait: tid0 polls with acquire LOADS (no RMW -> line stays shared).
__device__ __forceinline__ void wait_for(unsigned* c, unsigned tgt, int tid) {
  if (tid == 0) {
    while (__hip_atomic_load(c, __ATOMIC_ACQUIRE, __HIP_MEMORY_SCOPE_AGENT) <
           tgt)
      __builtin_amdgcn_s_sleep(2);
    __threadfence();
  }
  __syncthreads();
}

// ---------------------------------------------------------------------------
// MEGAKERNEL v2. grid 256 x 256 threads, all blocks work in A and C.
//  A) blocks < 16*S : split-K GEMM slice -> Gp        [ctr0 = 256]
//  B) blocks < 64   : slice-reduce, accuracy, LSEtab  [ctr1 = 256]
//  C) all 256 = 64 cls x 4 parts : class loss (MFMA)  [ctr2 = 256]
//  D) block 0       : final reduce -> out
// ---------------------------------------------------------------------------
__global__ __launch_bounds__(256, 2) void TransitionLoss_30666066494151_kernel(
    const float* __restrict__ F, const int* __restrict__ targets,
    unsigned* __restrict__ ctr, float* __restrict__ lsp,
    float* __restrict__ lan, float* __restrict__ cnts,
    float* __restrict__ flags, float* __restrict__ LSEtab,
    float* __restrict__ G, float* __restrict__ Gp,
    float* __restrict__ out, int n, int d, int S) {
  __shared__ SMem sm;
  const int tid = threadIdx.x;
  const int b = blockIdx.x;
  const int nn = n * n;
  const int nhalf = n >> 1;

  // ---------------- Phase A: GEMM slices ----------------
  if (b < 16 * S) {
    const int bx = b & 3, by = (b >> 2) & 3, kz = b >> 4;
    const int kchunk = d / S;
    const int ty = tid >> 4, tx = tid & 15;
    const int lrow = tid >> 2;
    const int lcol = (tid & 3) * 8;
    const float* Ap = F + (size_t)(bx * 64 + lrow) * d + (size_t)kz * kchunk + lcol;
    const float* Bp = F + (size_t)(by * 64 + lrow) * d + (size_t)kz * kchunk + lcol;
    float acc[4][4];
    for (int r = 0; r < 4; r++)
      for (int c = 0; c < 4; c++) acc[r][c] = 0.0f;

    for (int ks = 0; ks < kchunk; ks += 32) {
      float4 a0 = *(const float4*)(Ap + ks);
      float4 a1 = *(const float4*)(Ap + ks + 4);
      float4 b0 = *(const float4*)(Bp + ks);
      float4 b1 = *(const float4*)(Bp + ks + 4);
      __syncthreads();
      *(float4*)&sm.g.As[lrow][lcol]     = a0;
      *(float4*)&sm.g.As[lrow][lcol + 4] = a1;
      *(float4*)&sm.g.Bs[lrow][lcol]     = b0;
      *(float4*)&sm.g.Bs[lrow][lcol + 4] = b1;
      __syncthreads();
#pragma unroll
      for (int kk = 0; kk < 32; kk += 4) {
        float4 av[4], bv[4];
#pragma unroll
        for (int r = 0; r < 4; r++)
          av[r] = *(const float4*)&sm.g.As[ty + 16 * r][kk];
#pragma unroll
        for (int c = 0; c < 4; c++)
          bv[c] = *(const float4*)&sm.g.Bs[tx + 16 * c][kk];
#pragma unroll
        for (int r = 0; r < 4; r++) {
          float4 A = av[r];
#pragma unroll
          for (int c = 0; c < 4; c++) {
            float4 B = bv[c];
            acc[r][c] += A.x * B.x + A.y * B.y + A.z * B.z + A.w * B.w;
          }
        }
      }
    }
    float* Gs = Gp + (size_t)kz * nn;
#pragma unroll
    for (int r = 0; r < 4; r++)
#pragma unroll
      for (int c = 0; c < 4; c++)
        Gs[(size_t)(bx * 64 + ty + 16 * r) * n + (by * 64 + tx + 16 * c)] =
            acc[r][c];
  }

  arrive(&ctr[0], tid);

  // ---------------- Phase B: reduce + stats (blocks 0..63) ----------------
  if (b < 64) {
    wait_for(&ctr[0], 256, tid);
    const int lane = tid & 63;
    const int w = tid >> 6;
    sm.s.tg[tid] = targets[tid];
    {
      float s0 = 0.0f;
      for (int s = 0; s < S; s++)
        s0 += Gp[(size_t)s * nn + (size_t)tid * (n + 1)];
      sm.s.diag[tid] = s0;
    }
    if (tid < 128) sm.s.bins[tid >> 5][tid & 31] = 0.0f;
    __syncthreads();

    const int r = b * 4 + w;
    const int opp0 = (r < nhalf) ? nhalf : 0;
    const int myid = sm.s.tg[r];
    const float sqr = sm.s.diag[r];

    float4 v = make_float4(0.f, 0.f, 0.f, 0.f);
    for (int s = 0; s < S; s++) {
      float4 t = *(const float4*)(Gp + (size_t)s * nn + (size_t)r * n + lane * 4);
      v.x += t.x; v.y += t.y; v.z += t.z; v.w += t.w;
    }
    *(float4*)(G + (size_t)r * n + lane * 4) = v;
    float gv[4] = {v.x, v.y, v.z, v.w};

    float dap = -1e30f, dan = 1e30f;
#pragma unroll
    for (int q = 0; q < 4; q++) {
      int j = lane * 4 + q;
      float dist = sqrtf(fmaxf(sqr + sm.s.diag[j] - 2.0f * gv[q], EPSF));
      if (sm.s.tg[j] == myid) dap = fmaxf(dap, dist);
      else                    dan = fminf(dan, dist);
    }
#pragma unroll
    for (int off = 32; off; off >>= 1) {
      dap = fmaxf(dap, __shfl_xor(dap, off));
      dan = fminf(dan, __shfl_xor(dan, off));
    }
    if (lane == 0) flags[r] = (dan >= dap) ? 1.0f : 0.0f;

    float mx = -1e30f;
#pragma unroll
    for (int q = 0; q < 4; q++) {
      int j = lane * 4 + q;
      if (j >= opp0 && j < opp0 + nhalf) mx = fmaxf(mx, gv[q]);
    }
#pragma unroll
    for (int off = 32; off; off >>= 1) mx = fmaxf(mx, __shfl_xor(mx, off));

#pragma unroll
    for (int q = 0; q < 4; q++) {
      int j = lane * 4 + q;
      if (j >= opp0 && j < opp0 + nhalf)
        atomicAdd(&sm.s.bins[w][sm.s.tg[j]], __expf(gv[q] - mx));
    }
    __syncthreads();

    if (lane < 32) {
      float bb = sm.s.bins[w][lane];
      float lv = __shfl_up(bb, 1, 32);
      if (lane == 0) lv = 0.0f;
#pragma unroll
      for (int off = 1; off < 32; off <<= 1) {
        float t = __shfl_up(lv, off, 32);
        if (lane >= off) lv += t;
      }
      float rvv = __shfl_down(bb, 1, 32);
      if (lane == 31) rvv = 0.0f;
#pragma unroll
      for (int off = 1; off < 32; off <<= 1) {
        float t = __shfl_down(rvv, off, 32);
        if (lane + off < 32) rvv += t;
      }
      float excl = fmaxf(lv + rvv, 1e-37f);
      LSEtab[(size_t)lane * n + r] = mx + __logf(excl);  // [id][row]
    }
  }

  arrive(&ctr[1], tid);
  wait_for(&ctr[1], 256, tid);

  // ---------------- Phase C: class loss, 64 cls x 4 parts ----------------
  {
    const int cls = b >> 2;
    const int part = b & 3;            // rows [part*32, part*32+32)
    const int myid = cls & 31;
    const int hA = cls >> 5;
    const int rowA0 = hA * nhalf;
    const int colB0 = nhalf - rowA0;

    sm.c.tg[tid] = targets[tid];
    if (tid == 0) { sm.c.ctrP = 0; sm.c.ctrQ = 0; }
    __syncthreads();

    if (tid < 128) {
      sm.c.maskA[tid] = (sm.c.tg[rowA0 + tid] != myid) ? 1 : 0;
      sm.c.Ri[tid] = LSEtab[(size_t)myid * n + rowA0 + tid];
    } else {
      sm.c.maskB[tid - 128] = (sm.c.tg[colB0 + tid - 128] != myid) ? 1 : 0;
      sm.c.Cl[tid - 128] = LSEtab[(size_t)myid * n + colB0 + tid - 128];
    }
    if (sm.c.tg[tid] == myid) {
      int inAhalf = (((tid >= nhalf) ? 1 : 0) == hA) ? 1 : 0;
      if (inAhalf) { int k = atomicAdd(&sm.c.ctrP, 1); if (k < 16) sm.c.Plist[k] = tid; }
      else         { int k = atomicAdd(&sm.c.ctrQ, 1); if (k < 16) sm.c.Qlist[k] = tid; }
    }
    __syncthreads();
    const int nP = min(sm.c.ctrP, 16), nQ = min(sm.c.ctrQ, 16);

#pragma unroll
    for (int k8 = 0; k8 < 2; k8++) {
      float4 g[8];
#pragma unroll
      for (int u = 0; u < 8; u++) {
        int e4 = tid + 256 * (k8 * 8 + u);
        int i = e4 >> 5;
        int l4 = (e4 & 31) << 2;
        g[u] = *(const float4*)(G + (size_t)(rowA0 + i) * n + colB0 + l4);
      }
#pragma unroll
      for (int u = 0; u < 8; u++) {
        int e4 = tid + 256 * (k8 * 8 + u);
        int i = e4 >> 5;
        int l4 = (e4 & 31) << 2;
        float rih = 0.5f * sm.c.Ri[i];
        int ma = sm.c.maskA[i];
        float w0 = (ma && sm.c.maskB[l4 + 0]) ? __expf(g[u].x - rih - 0.5f * sm.c.Cl[l4 + 0]) : 0.0f;
        float w1 = (ma && sm.c.maskB[l4 + 1]) ? __expf(g[u].y - rih - 0.5f * sm.c.Cl[l4 + 1]) : 0.0f;
        float w2 = (ma && sm.c.maskB[l4 + 2]) ? __expf(g[u].z - rih - 0.5f * sm.c.Cl[l4 + 2]) : 0.0f;
        float w3 = (ma && sm.c.maskB[l4 + 3]) ? __expf(g[u].w - rih - 0.5f * sm.c.Cl[l4 + 3]) : 0.0f;
        uint2 packed;
        packed.x = (unsigned)f2bf(w0) | ((unsigned)f2bf(w1) << 16);
        packed.y = (unsigned)f2bf(w2) | ((unsigned)f2bf(w3) << 16);
        *(uint2*)&sm.c.W[i][l4] = packed;
      }
    }

    if (part == 0) {
      int p = tid >> 4, q = tid & 15;
      float v = 0.0f;
      if (p < nP && q < nQ) v = G[(size_t)sm.c.Plist[p] * n + sm.c.Qlist[q]];
      sm.c.SMRAW[p][q] = v;
    }
    __syncthreads();

    // MFMA: 32 output rows x 128 cols = 8 tiles/wave... 16 tiles over 4
    // waves -> wave wv does row-tile rt = part*2 + (wv>>1), col-tiles
    // (wv&1)*4 .. +4. C/D map (m89): row = rt*16 + kh*4 + e, col = ct*16+m16.
    const int lane = tid & 63;
    const int wv = tid >> 6;
    const int m16 = lane & 15;
    const int kh = lane >> 4;
    const int rt = part * 2 + (wv >> 1);
    const int c0 = (wv & 1) * 4;
    f32x4 acc[4];
#pragma unroll
    for (int c = 0; c < 4; c++) acc[c] = (f32x4){0.f, 0.f, 0.f, 0.f};

#pragma unroll
    for (int kc = 0; kc < 4; kc++) {
      const int koff = kc * 32 + kh * 8;
      bf16x8 afrag = *(const bf16x8*)&sm.c.W[rt * 16 + m16][koff];
#pragma unroll
      for (int c = 0; c < 4; c++) {
        bf16x8 bfrag = *(const bf16x8*)&sm.c.W[(c0 + c) * 16 + m16][koff];
        acc[c] = __builtin_amdgcn_mfma_f32_16x16x32_bf16(afrag, bfrag, acc[c],
                                                         0, 0, 0);
      }
    }

    float lsum = 0.0f;
#pragma unroll
    for (int c = 0; c < 4; c++) {
      f32x4 D = acc[c];
      int jcol = (c0 + c) * 16 + m16;
      float rj = sm.c.Ri[jcol];
#pragma unroll
      for (int e = 0; e < 4; e++) {
        int irow = rt * 16 + kh * 4 + e;
        float t = __expf(0.5f * (rj - sm.c.Ri[irow])) * D[e];
        lsum += fmaxf(sqrtf(fmaxf(t, EPSF)) - 0.2f, 0.0f);
      }
    }
    sm.c.red[tid] = lsum;
    __syncthreads();
    for (int s2 = 128; s2 > 0; s2 >>= 1) {
      if (tid < s2) sm.c.red[tid] += sm.c.red[tid + s2];
      __syncthreads();
    }
    if (tid == 0) lsp[cls * 4 + part] = sm.c.red[0];

    if (part == 0) {
      __syncthreads();
      sm.c.red[tid] = (tid < 128) ? (float)sm.c.maskA[tid] : 0.0f;
      __syncthreads();
      for (int s2 = 128; s2 > 0; s2 >>= 1) {
        if (tid < s2) sm.c.red[tid] += sm.c.red[tid + s2];
        __syncthreads();
      }
      if (tid == 0) { cnts[cls * 2 + 0] = sm.c.red[0]; cnts[cls * 2 + 1] = (float)nP; }

      if (tid < nP) {
        float mx = -1e30f;
        for (int q = 0; q < nQ; q++) mx = fmaxf(mx, sm.c.SMRAW[tid][q]);
        float s = 0.0f;
        for (int q = 0; q < nQ; q++) s += __expf(sm.c.SMRAW[tid][q] - mx);
        for (int q = 0; q < nQ; q++)
          sm.c.SP[tid][q] = __expf(sm.c.SMRAW[tid][q] - mx) / s;
      }
      if (tid >= 64 && tid < 64 + nQ) {
        int q = tid - 64;
        float mx = -1e30f;
        for (int p = 0; p < nP; p++) mx = fmaxf(mx, sm.c.SMRAW[p][q]);
        float s = 0.0f;
        for (int p = 0; p < nP; p++) s += __expf(sm.c.SMRAW[p][q] - mx);
        for (int p = 0; p < nP; p++)
          sm.c.SQ[q][p] = __expf(sm.c.SMRAW[p][q] - mx) / s;
      }
      __syncthreads();
      float lv = 0.0f;
      if (tid < nP * nP) {
        int i = tid / nP, j = tid - i * nP;
        float t = 0.0f;
        for (int l = 0; l < nQ; l++) t += sm.c.SP[i][l] * sm.c.SQ[l][j];
        lv = fmaxf(0.5f - sqrtf(fmaxf(t, EPSF)), 0.0f);
      }
      sm.c.red[tid] = lv;
      __syncthreads();
      for (int s2 = 128; s2 > 0; s2 >>= 1) {
        if (tid < s2) sm.c.red[tid] += sm.c.red[tid + s2];
        __syncthreads();
      }
      if (tid == 0) lan[cls] = sm.c.red[0];
    }
  }

  arrive(&ctr[2], tid);
  if (b != 0) return;
  wait_for(&ctr[2], 256, tid);

  // ---------------- Phase D: final reduce (block 0) ----------------
  {
    float lv = 0.0f;
    if (tid < 64) {
      float nA = cnts[tid * 2 + 0];
      float nP = cnts[tid * 2 + 1];
      if (nP > 0.5f && nA > 0.5f) {
        float s = lsp[tid * 4 + 0] + lsp[tid * 4 + 1] + lsp[tid * 4 + 2] +
                  lsp[tid * 4 + 3];
        lv = nP * (s / (nA * nA) + lan[tid] / (nP * nP));
      }
    }
    sm.f.rl[tid] = lv;
    sm.f.rf[tid] = flags[tid];
    __syncthreads();
    for (int s2 = 128; s2 > 0; s2 >>= 1) {
      if (tid < s2) {
        sm.f.rl[tid] += sm.f.rl[tid + s2];
        sm.f.rf[tid] += sm.f.rf[tid + s2];
      }
      __syncthreads();
    }
    if (tid == 0) {
      out[0] = sm.f.rl[0] / (float)n;
      out[1] = sm.f.rf[0];
    }
  }
}

extern "C" void kernel_launch(void* const* d_in, const int* in_sizes, int n_in,
                              void* d_out, int out_size, void* d_ws,
                              size_t ws_size, hipStream_t stream) {
  const float* feature = (const float*)d_in[0];
  const int* targets = (const int*)d_in[1];
  const int n = in_sizes[1];            // 256
  const int d = in_sizes[0] / n;        // 2048
  const int nn = n * n;
  const size_t smallf = 16 + 256 + 64 + 128 + 256 + (size_t)n * 32;

  int S = 1;
  if (ws_size >= (smallf + nn + (size_t)16 * nn) * sizeof(float)) S = 16;
  else if (ws_size >= (smallf + nn + (size_t)4 * nn) * sizeof(float)) S = 4;

  unsigned* ctr = (unsigned*)d_ws;      // 16 uints (barrier counters)
  float* base = (float*)d_ws + 16;
  float* lsp = base;                    // 256 (64 cls x 4 parts)
  float* lan = lsp + 256;               // 64
  float* cnts = lan + 64;               // 128
  float* flags = cnts + 128;            // 256
  float* LSEtab = flags + 256;          // 32*n ([id][row])
  float* G = LSEtab + (size_t)n * 32;   // nn
  float* Gp = (S > 1) ? (G + nn) : G;   // S*nn (alias G when S==1)
  float* out = (float*)d_out;

  hipMemsetAsync(d_ws, 0, 16 * sizeof(unsigned), stream);

  TransitionLoss_30666066494151_kernel<<<256, 256, 0, stream>>>(
      feature, targets, ctr, lsp, lan, cnts, flags, LSEtab, G, Gp, out, n, d, S);
}

// Round 21
// 70.583 us; speedup vs baseline: 2.5585x; 2.1525x over previous
//
#include <hip/hip_runtime.h>

#define EPSF 1e-12f

__device__ __forceinline__ unsigned short f2bf(float f) {
  unsigned int u = __float_as_uint(f);
  unsigned int r = u + 0x7fffu + ((u >> 16) & 1u);  // RNE
  return (unsigned short)(r >> 16);
}
#define BFLO(u) __uint_as_float((u) << 16)
#define BFHI(u) __uint_as_float((u) & 0xffff0000u)

// ---------------------------------------------------------------------------
// Kernel 1: partial G slices (split-K). grid (n/64, n/64, S), block 256.
// ---------------------------------------------------------------------------
__global__ void gemm_tile(const float* __restrict__ F, float* __restrict__ Gout,
                          int n, int d, int kchunk) {
  __shared__ float As[64][36];
  __shared__ float Bs[64][36];
  const int tid = threadIdx.x;
  const int bx = blockIdx.x, by = blockIdx.y, kz = blockIdx.z;
  const int ty = tid >> 4, tx = tid & 15;
  const int lrow = tid >> 2;
  const int lcol = (tid & 3) * 8;
  const float* Ap = F + (size_t)(bx * 64 + lrow) * d + (size_t)kz * kchunk + lcol;
  const float* Bp = F + (size_t)(by * 64 + lrow) * d + (size_t)kz * kchunk + lcol;
  float acc[4][4];
  for (int r = 0; r < 4; r++)
    for (int c = 0; c < 4; c++) acc[r][c] = 0.0f;

  for (int ks = 0; ks < kchunk; ks += 32) {
    float4 a0 = *(const float4*)(Ap + ks);
    float4 a1 = *(const float4*)(Ap + ks + 4);
    float4 b0 = *(const float4*)(Bp + ks);
    float4 b1 = *(const float4*)(Bp + ks + 4);
    __syncthreads();
    *(float4*)&As[lrow][lcol]     = a0;
    *(float4*)&As[lrow][lcol + 4] = a1;
    *(float4*)&Bs[lrow][lcol]     = b0;
    *(float4*)&Bs[lrow][lcol + 4] = b1;
    __syncthreads();
#pragma unroll
    for (int kk = 0; kk < 32; kk += 4) {
      float4 av[4], bv[4];
#pragma unroll
      for (int r = 0; r < 4; r++) av[r] = *(const float4*)&As[ty + 16 * r][kk];
#pragma unroll
      for (int c = 0; c < 4; c++) bv[c] = *(const float4*)&Bs[tx + 16 * c][kk];
#pragma unroll
      for (int r = 0; r < 4; r++) {
        float4 A = av[r];
#pragma unroll
        for (int c = 0; c < 4; c++) {
          float4 B = bv[c];
          acc[r][c] += A.x * B.x + A.y * B.y + A.z * B.z + A.w * B.w;
        }
      }
    }
  }
  float* Gs = Gout + (size_t)kz * n * n;
#pragma unroll
  for (int r = 0; r < 4; r++)
#pragma unroll
    for (int c = 0; c < 4; c++)
      Gs[(size_t)(bx * 64 + ty + 16 * r) * n + (by * 64 + tx + 16 * c)] =
          acc[r][c];
}

// ---------------------------------------------------------------------------
// Kernel 2: fused slice-reduce + stats (r18-validated). grid 64 x 256.
// Per row r: sum S slices -> G row; accuracy flag; LSE[id][r] table.
// ---------------------------------------------------------------------------
__global__ void stats_kernel(const float* __restrict__ Gp,
                             const int* __restrict__ targets,
                             float* __restrict__ G, float* __restrict__ LSEtab,
                             float* __restrict__ flags, int n, int S) {
  __shared__ float bins[4][33];
  __shared__ int tg[256];
  __shared__ float diag[256];
  const int tid = threadIdx.x;
  const int lane = tid & 63;
  const int w = tid >> 6;
  const int nn = n * n;
  tg[tid] = targets[tid];
  {
    float s0 = 0.0f;
    for (int s = 0; s < S; s++)
      s0 += Gp[(size_t)s * nn + (size_t)tid * (n + 1)];
    diag[tid] = s0;
  }
  if (tid < 128) bins[tid >> 5][tid & 31] = 0.0f;
  __syncthreads();

  const int r = blockIdx.x * 4 + w;
  const int nhalf = n >> 1;
  const int opp0 = (r < nhalf) ? nhalf : 0;
  const int myid = tg[r];
  const float sqr = diag[r];

  float4 v = make_float4(0.f, 0.f, 0.f, 0.f);
  for (int s = 0; s < S; s++) {
    float4 t = *(const float4*)(Gp + (size_t)s * nn + (size_t)r * n + lane * 4);
    v.x += t.x; v.y += t.y; v.z += t.z; v.w += t.w;
  }
  *(float4*)(G + (size_t)r * n + lane * 4) = v;
  float gv[4] = {v.x, v.y, v.z, v.w};

  float dap = -1e30f, dan = 1e30f;
#pragma unroll
  for (int q = 0; q < 4; q++) {
    int j = lane * 4 + q;
    float dist = sqrtf(fmaxf(sqr + diag[j] - 2.0f * gv[q], EPSF));
    if (tg[j] == myid) dap = fmaxf(dap, dist);
    else               dan = fminf(dan, dist);
  }
#pragma unroll
  for (int off = 32; off; off >>= 1) {
    dap = fmaxf(dap, __shfl_xor(dap, off));
    dan = fminf(dan, __shfl_xor(dan, off));
  }
  if (lane == 0) flags[r] = (dan >= dap) ? 1.0f : 0.0f;

  float mx = -1e30f;
#pragma unroll
  for (int q = 0; q < 4; q++) {
    int j = lane * 4 + q;
    if (j >= opp0 && j < opp0 + nhalf) mx = fmaxf(mx, gv[q]);
  }
#pragma unroll
  for (int off = 32; off; off >>= 1) mx = fmaxf(mx, __shfl_xor(mx, off));

#pragma unroll
  for (int q = 0; q < 4; q++) {
    int j = lane * 4 + q;
    if (j >= opp0 && j < opp0 + nhalf)
      atomicAdd(&bins[w][tg[j]], __expf(gv[q] - mx));
  }
  __syncthreads();

  if (lane < 32) {
    float b = bins[w][lane];
    float lv = __shfl_up(b, 1, 32);
    if (lane == 0) lv = 0.0f;
#pragma unroll
    for (int off = 1; off < 32; off <<= 1) {
      float t = __shfl_up(lv, off, 32);
      if (lane >= off) lv += t;
    }
    float rv = __shfl_down(b, 1, 32);
    if (lane == 31) rv = 0.0f;
#pragma unroll
    for (int off = 1; off < 32; off <<= 1) {
      float t = __shfl_down(rv, off, 32);
      if (lane + off < 32) rv += t;
    }
    float excl = fmaxf(lv + rv, 1e-37f);
    LSEtab[(size_t)lane * n + r] = mx + __logf(excl);  // [id][row]
  }
}

// ---------------------------------------------------------------------------
// Kernel 3: class loss (r16 body, grid (64,8)) + LAST-BLOCK final reduce.
// ---------------------------------------------------------------------------
__global__ __launch_bounds__(256, 2) void TransitionLoss_30666066494151_kernel(
    const float* __restrict__ G, const int* __restrict__ targets,
    const float* __restrict__ LSEtab, float* __restrict__ lsp,
    float* __restrict__ lan, float* __restrict__ cnts,
    const float* __restrict__ flags, unsigned* __restrict__ ticket,
    float* __restrict__ out, int n) {
  __shared__ unsigned short W[128][136];   // 34816 B bf16
  __shared__ int tg[256];
  __shared__ int maskA[128], maskB[128];
  __shared__ float Ri[128], Cl[128];
  __shared__ float SMRAW[16][17];
  __shared__ float SP[16][17], SQ[16][17];
  __shared__ float red[256], red2[256];
  __shared__ int Plist[16], Qlist[16];
  __shared__ int ctrP, ctrQ;
  __shared__ int islast;

  const int tid = threadIdx.x;
  const int cls = blockIdx.x;
  const int part = blockIdx.y;      // 0..7 -> rows [part*16, part*16+16)
  const int nhalf = n >> 1;
  const int myid = cls & 31;
  const int hA = cls >> 5;
  const int rowA0 = hA * nhalf;
  const int colB0 = nhalf - rowA0;

  tg[tid] = targets[tid];
  if (tid == 0) { ctrP = 0; ctrQ = 0; }
  __syncthreads();

  if (tid < 128) {
    maskA[tid] = (tg[rowA0 + tid] != myid) ? 1 : 0;
    Ri[tid] = LSEtab[(size_t)myid * n + rowA0 + tid];   // [id][row], coalesced
  } else {
    maskB[tid - 128] = (tg[colB0 + tid - 128] != myid) ? 1 : 0;
    Cl[tid - 128] = LSEtab[(size_t)myid * n + colB0 + tid - 128];
  }
  if (tg[tid] == myid) {
    int inAhalf = (((tid >= nhalf) ? 1 : 0) == hA) ? 1 : 0;
    if (inAhalf) { int k = atomicAdd(&ctrP, 1); if (k < 16) Plist[k] = tid; }
    else         { int k = atomicAdd(&ctrQ, 1); if (k < 16) Qlist[k] = tid; }
  }
  __syncthreads();
  const int nP = min(ctrP, 16), nQ = min(ctrQ, 16);

  // Fused load + W fill (bf16): 16 float4, 8 in flight per group.
#pragma unroll
  for (int k8 = 0; k8 < 2; k8++) {
    float4 g[8];
#pragma unroll
    for (int u = 0; u < 8; u++) {
      int e4 = tid + 256 * (k8 * 8 + u);
      int i = e4 >> 5;
      int l4 = (e4 & 31) << 2;
      g[u] = *(const float4*)(G + (size_t)(rowA0 + i) * n + colB0 + l4);
    }
#pragma unroll
    for (int u = 0; u < 8; u++) {
      int e4 = tid + 256 * (k8 * 8 + u);
      int i = e4 >> 5;
      int l4 = (e4 & 31) << 2;
      float rih = 0.5f * Ri[i];
      int ma = maskA[i];
      float w0 = (ma && maskB[l4 + 0]) ? __expf(g[u].x - rih - 0.5f * Cl[l4 + 0]) : 0.0f;
      float w1 = (ma && maskB[l4 + 1]) ? __expf(g[u].y - rih - 0.5f * Cl[l4 + 1]) : 0.0f;
      float w2 = (ma && maskB[l4 + 2]) ? __expf(g[u].z - rih - 0.5f * Cl[l4 + 2]) : 0.0f;
      float w3 = (ma && maskB[l4 + 3]) ? __expf(g[u].w - rih - 0.5f * Cl[l4 + 3]) : 0.0f;
      uint2 packed;
      packed.x = (unsigned)f2bf(w0) | ((unsigned)f2bf(w1) << 16);
      packed.y = (unsigned)f2bf(w2) | ((unsigned)f2bf(w3) << 16);
      *(uint2*)&W[i][l4] = packed;
    }
  }

  // t_pos parallel gather (part 0 only): one latency round.
  if (part == 0) {
    int p = tid >> 4, q = tid & 15;
    float v = 0.0f;
    if (p < nP && q < nQ) v = G[(size_t)Plist[p] * n + Qlist[q]];
    SMRAW[p][q] = v;
  }
  __syncthreads();

  // SYRK: rows [part*16 .. +16) x 128 cols, K=128 bf16 from LDS.
  const int i0 = part * 16;
  const int ty = tid >> 4, tx = tid & 15;
  const float riA = Ri[i0 + ty];
  float acc[8];
#pragma unroll
  for (int c = 0; c < 8; c++) acc[c] = 0.0f;

  for (int kk = 0; kk < 128; kk += 8) {
    uint4 ar = *(const uint4*)&W[i0 + ty][kk];
    uint4 br[8];
#pragma unroll
    for (int c = 0; c < 8; c++) br[c] = *(const uint4*)&W[tx + 16 * c][kk];
    float a0 = BFLO(ar.x), a1 = BFHI(ar.x), a2 = BFLO(ar.y), a3 = BFHI(ar.y);
    float a4 = BFLO(ar.z), a5 = BFHI(ar.z), a6 = BFLO(ar.w), a7 = BFHI(ar.w);
#pragma unroll
    for (int c = 0; c < 8; c++) {
      acc[c] += a0 * BFLO(br[c].x) + a1 * BFHI(br[c].x) +
                a2 * BFLO(br[c].y) + a3 * BFHI(br[c].y) +
                a4 * BFLO(br[c].z) + a5 * BFHI(br[c].z) +
                a6 * BFLO(br[c].w) + a7 * BFHI(br[c].w);
    }
  }

  float lsum = 0.0f;
#pragma unroll
  for (int c = 0; c < 8; c++) {
    int j = tx + 16 * c;
    float t = __expf(0.5f * (Ri[j] - riA)) * acc[c];
    lsum += fmaxf(sqrtf(fmaxf(t, EPSF)) - 0.2f, 0.0f);
  }
  red[tid] = lsum;
  __syncthreads();
  for (int s2 = 128; s2 > 0; s2 >>= 1) {
    if (tid < s2) red[tid] += red[tid + s2];
    __syncthreads();
  }
  if (tid == 0) lsp[cls * 8 + part] = red[0];

  if (part == 0) {
    __syncthreads();
    red[tid] = (tid < 128) ? (float)maskA[tid] : 0.0f;
    __syncthreads();
    for (int s2 = 128; s2 > 0; s2 >>= 1) {
      if (tid < s2) red[tid] += red[tid + s2];
      __syncthreads();
    }
    if (tid == 0) { cnts[cls * 2 + 0] = red[0]; cnts[cls * 2 + 1] = (float)nP; }

    if (tid < nP) {
      float mx = -1e30f;
      for (int q = 0; q < nQ; q++) mx = fmaxf(mx, SMRAW[tid][q]);
      float s = 0.0f;
      for (int q = 0; q < nQ; q++) s += __expf(SMRAW[tid][q] - mx);
      for (int q = 0; q < nQ; q++) SP[tid][q] = __expf(SMRAW[tid][q] - mx) / s;
    }
    if (tid >= 64 && tid < 64 + nQ) {
      int q = tid - 64;
      float mx = -1e30f;
      for (int p = 0; p < nP; p++) mx = fmaxf(mx, SMRAW[p][q]);
      float s = 0.0f;
      for (int p = 0; p < nP; p++) s += __expf(SMRAW[p][q] - mx);
      for (int p = 0; p < nP; p++) SQ[q][p] = __expf(SMRAW[p][q] - mx) / s;
    }
    __syncthreads();
    float lv = 0.0f;
    if (tid < nP * nP) {
      int i = tid / nP, j = tid - i * nP;
      float t = 0.0f;
      for (int l = 0; l < nQ; l++) t += SP[i][l] * SQ[l][j];
      lv = fmaxf(0.5f - sqrtf(fmaxf(t, EPSF)), 0.0f);
    }
    red[tid] = lv;
    __syncthreads();
    for (int s2 = 128; s2 > 0; s2 >>= 1) {
      if (tid < s2) red[tid] += red[tid + s2];
      __syncthreads();
    }
    if (tid == 0) lan[cls] = red[0];
  }

  // ---- last-block-done final reduce (one atomic per block, no polling) ----
  __syncthreads();
  if (tid == 0) {
    __threadfence();
    unsigned t = atomicAdd(ticket, 1u);
    islast = (t == gridDim.x * gridDim.y - 1) ? 1 : 0;
  }
  __syncthreads();
  if (islast) {
    __threadfence();  // acquire: all other blocks' writes are visible
    float lv = 0.0f;
    if (tid < 64) {
      float nA = cnts[tid * 2 + 0];
      float nP2 = cnts[tid * 2 + 1];
      if (nP2 > 0.5f && nA > 0.5f) {
        float s = 0.0f;
        for (int p = 0; p < 8; p++) s += lsp[tid * 8 + p];
        lv = nP2 * (s / (nA * nA) + lan[tid] / (nP2 * nP2));
      }
    }
    red[tid] = lv;
    red2[tid] = flags[tid];
    __syncthreads();
    for (int s2 = 128; s2 > 0; s2 >>= 1) {
      if (tid < s2) { red[tid] += red[tid + s2]; red2[tid] += red2[tid + s2]; }
      __syncthreads();
    }
    if (tid == 0) {
      out[0] = red[0] / (float)n;
      out[1] = red2[0];
    }
  }
}

extern "C" void kernel_launch(void* const* d_in, const int* in_sizes, int n_in,
                              void* d_out, int out_size, void* d_ws,
                              size_t ws_size, hipStream_t stream) {
  const float* feature = (const float*)d_in[0];
  const int* targets = (const int*)d_in[1];
  const int n = in_sizes[1];            // 256
  const int d = in_sizes[0] / n;        // 2048
  const int nn = n * n;
  const size_t smallf = 16 + 512 + 64 + 128 + 256 + (size_t)n * 32;

  int S = 1;
  if (ws_size >= (smallf + nn + (size_t)16 * nn) * sizeof(float)) S = 16;
  else if (ws_size >= (smallf + nn + (size_t)4 * nn) * sizeof(float)) S = 4;

  unsigned* ticket = (unsigned*)d_ws;   // 16 uints
  float* base = (float*)d_ws + 16;
  float* lsp = base;                    // 512
  float* lan = lsp + 512;               // 64
  float* cnts = lan + 64;               // 128
  float* flags = cnts + 128;            // 256
  float* LSEtab = flags + 256;          // 32*n ([id][row])
  float* G = LSEtab + (size_t)n * 32;   // nn
  float* Gp = (S > 1) ? (G + nn) : G;   // S*nn (alias G when S==1)
  float* out = (float*)d_out;

  hipMemsetAsync(d_ws, 0, 16 * sizeof(unsigned), stream);

  dim3 gg(n / 64, n / 64, S);
  gemm_tile<<<gg, 256, 0, stream>>>(feature, Gp, n, d, d / S);

  stats_kernel<<<n / 4, 256, 0, stream>>>(Gp, targets, G, LSEtab, flags, n, S);

  dim3 gc(64, 8);
  TransitionLoss_30666066494151_kernel<<<gc, 256, 0, stream>>>(
      G, targets, LSEtab, lsp, lan, cnts, flags, ticket, out, n);
}

// Round 22
// 56.604 us; speedup vs baseline: 3.1904x; 1.2470x over previous
//
#include <hip/hip_runtime.h>

#define EPSF 1e-12f

__device__ __forceinline__ unsigned short f2bf(float f) {
  unsigned int u = __float_as_uint(f);
  unsigned int r = u + 0x7fffu + ((u >> 16) & 1u);  // RNE
  return (unsigned short)(r >> 16);
}
#define BFLO(u) __uint_as_float((u) << 16)
#define BFHI(u) __uint_as_float((u) & 0xffff0000u)

// ---------------------------------------------------------------------------
// Kernel 1: partial G slices (split-K). grid (n/64, n/64, S), block 256.
// ---------------------------------------------------------------------------
__global__ void gemm_tile(const float* __restrict__ F, float* __restrict__ Gout,
                          int n, int d, int kchunk) {
  __shared__ float As[64][36];
  __shared__ float Bs[64][36];
  const int tid = threadIdx.x;
  const int bx = blockIdx.x, by = blockIdx.y, kz = blockIdx.z;
  const int ty = tid >> 4, tx = tid & 15;
  const int lrow = tid >> 2;
  const int lcol = (tid & 3) * 8;
  const float* Ap = F + (size_t)(bx * 64 + lrow) * d + (size_t)kz * kchunk + lcol;
  const float* Bp = F + (size_t)(by * 64 + lrow) * d + (size_t)kz * kchunk + lcol;
  float acc[4][4];
  for (int r = 0; r < 4; r++)
    for (int c = 0; c < 4; c++) acc[r][c] = 0.0f;

  for (int ks = 0; ks < kchunk; ks += 32) {
    float4 a0 = *(const float4*)(Ap + ks);
    float4 a1 = *(const float4*)(Ap + ks + 4);
    float4 b0 = *(const float4*)(Bp + ks);
    float4 b1 = *(const float4*)(Bp + ks + 4);
    __syncthreads();
    *(float4*)&As[lrow][lcol]     = a0;
    *(float4*)&As[lrow][lcol + 4] = a1;
    *(float4*)&Bs[lrow][lcol]     = b0;
    *(float4*)&Bs[lrow][lcol + 4] = b1;
    __syncthreads();
#pragma unroll
    for (int kk = 0; kk < 32; kk += 4) {
      float4 av[4], bv[4];
#pragma unroll
      for (int r = 0; r < 4; r++) av[r] = *(const float4*)&As[ty + 16 * r][kk];
#pragma unroll
      for (int c = 0; c < 4; c++) bv[c] = *(const float4*)&Bs[tx + 16 * c][kk];
#pragma unroll
      for (int r = 0; r < 4; r++) {
        float4 A = av[r];
#pragma unroll
        for (int c = 0; c < 4; c++) {
          float4 B = bv[c];
          acc[r][c] += A.x * B.x + A.y * B.y + A.z * B.z + A.w * B.w;
        }
      }
    }
  }
  float* Gs = Gout + (size_t)kz * n * n;
#pragma unroll
  for (int r = 0; r < 4; r++)
#pragma unroll
    for (int c = 0; c < 4; c++)
      Gs[(size_t)(bx * 64 + ty + 16 * r) * n + (by * 64 + tx + 16 * c)] =
          acc[r][c];
}

__global__ void reduce_slices(const float* __restrict__ Gp,
                              float* __restrict__ G, int nn, int nslices) {
  int e = (blockIdx.x * 256 + threadIdx.x) * 4;
  if (e < nn) {
    float4 s = *(const float4*)(Gp + e);
    for (int k = 1; k < nslices; k++) {
      float4 t = *(const float4*)(Gp + (size_t)k * nn + e);
      s.x += t.x; s.y += t.y; s.z += t.z; s.w += t.w;
    }
    *(float4*)(G + e) = s;
  }
}

// ---------------------------------------------------------------------------
// Fused stats kernel: accuracy flags + LSE[r][id] table. grid 64 x 256.
// ---------------------------------------------------------------------------
__global__ void stats_kernel(const float* __restrict__ G,
                             const int* __restrict__ targets,
                             float* __restrict__ LSEtab,
                             float* __restrict__ flags, int n) {
  __shared__ float bins[4][33];
  __shared__ int tg[256];
  __shared__ float diag[256];
  const int tid = threadIdx.x;
  const int lane = tid & 63;
  const int w = tid >> 6;
  tg[tid] = targets[tid];
  diag[tid] = G[(size_t)tid * (n + 1)];
  if (tid < 128) bins[tid >> 5][tid & 31] = 0.0f;
  __syncthreads();

  const int r = blockIdx.x * 4 + w;
  const int nhalf = n >> 1;
  const int opp0 = (r < nhalf) ? nhalf : 0;
  const int myid = tg[r];
  const float sqr = diag[r];

  float4 v = *(const float4*)(G + (size_t)r * n + lane * 4);
  float gv[4] = {v.x, v.y, v.z, v.w};

  float dap = -1e30f, dan = 1e30f;
#pragma unroll
  for (int q = 0; q < 4; q++) {
    int j = lane * 4 + q;
    float dist = sqrtf(fmaxf(sqr + diag[j] - 2.0f * gv[q], EPSF));
    if (tg[j] == myid) dap = fmaxf(dap, dist);
    else               dan = fminf(dan, dist);
  }
#pragma unroll
  for (int off = 32; off; off >>= 1) {
    dap = fmaxf(dap, __shfl_xor(dap, off));
    dan = fminf(dan, __shfl_xor(dan, off));
  }
  if (lane == 0) flags[r] = (dan >= dap) ? 1.0f : 0.0f;

  float mx = -1e30f;
#pragma unroll
  for (int q = 0; q < 4; q++) {
    int j = lane * 4 + q;
    if (j >= opp0 && j < opp0 + nhalf) mx = fmaxf(mx, gv[q]);
  }
#pragma unroll
  for (int off = 32; off; off >>= 1) mx = fmaxf(mx, __shfl_xor(mx, off));

#pragma unroll
  for (int q = 0; q < 4; q++) {
    int j = lane * 4 + q;
    if (j >= opp0 && j < opp0 + nhalf)
      atomicAdd(&bins[w][tg[j]], __expf(gv[q] - mx));
  }
  __syncthreads();

  if (lane < 32) {
    float b = bins[w][lane];
    float lv = __shfl_up(b, 1, 32);
    if (lane == 0) lv = 0.0f;
#pragma unroll
    for (int off = 1; off < 32; off <<= 1) {
      float t = __shfl_up(lv, off, 32);
      if (lane >= off) lv += t;
    }
    float rv = __shfl_down(b, 1, 32);
    if (lane == 31) rv = 0.0f;
#pragma unroll
    for (int off = 1; off < 32; off <<= 1) {
      float t = __shfl_down(rv, off, 32);
      if (lane + off < 32) rv += t;
    }
    float excl = fmaxf(lv + rv, 1e-37f);
    LSEtab[(size_t)r * 32 + lane] = mx + __logf(excl);
  }
}

// ---------------------------------------------------------------------------
// Class-dedup loss kernel. grid (64 classes, 8 row-parts), block 256.
// __launch_bounds__(256,2): independent-register B-column reads (ILP).
// ---------------------------------------------------------------------------
__global__ __launch_bounds__(256, 2) void TransitionLoss_30666066494151_kernel(
    const float* __restrict__ G, const int* __restrict__ targets,
    const float* __restrict__ LSEtab, float* __restrict__ lsp,
    float* __restrict__ lan, float* __restrict__ cnts, int n) {
  __shared__ unsigned short W[128][136];   // 34816 B bf16
  __shared__ int tg[256];
  __shared__ int maskA[128], maskB[128];
  __shared__ float Ri[128], Cl[128];
  __shared__ float SMRAW[16][17];
  __shared__ float SP[16][17], SQ[16][17];
  __shared__ float red[256];
  __shared__ int Plist[16], Qlist[16];
  __shared__ int ctrP, ctrQ;

  const int tid = threadIdx.x;
  const int cls = blockIdx.x;
  const int part = blockIdx.y;      // 0..7 -> rows [part*16, part*16+16)
  const int nhalf = n >> 1;
  const int myid = cls & 31;
  const int hA = cls >> 5;
  const int rowA0 = hA * nhalf;
  const int colB0 = nhalf - rowA0;

  tg[tid] = targets[tid];
  if (tid == 0) { ctrP = 0; ctrQ = 0; }
  __syncthreads();

  if (tid < 128) {
    maskA[tid] = (tg[rowA0 + tid] != myid) ? 1 : 0;
    Ri[tid] = LSEtab[(size_t)(rowA0 + tid) * 32 + myid];
  } else {
    maskB[tid - 128] = (tg[colB0 + tid - 128] != myid) ? 1 : 0;
    Cl[tid - 128] = LSEtab[(size_t)(colB0 + tid - 128) * 32 + myid];
  }
  if (tg[tid] == myid) {
    int inAhalf = (((tid >= nhalf) ? 1 : 0) == hA) ? 1 : 0;
    if (inAhalf) { int k = atomicAdd(&ctrP, 1); if (k < 16) Plist[k] = tid; }
    else         { int k = atomicAdd(&ctrQ, 1); if (k < 16) Qlist[k] = tid; }
  }
  __syncthreads();
  const int nP = min(ctrP, 16), nQ = min(ctrQ, 16);

  // Fused load + W fill (bf16): 16 float4, 8 in flight per group.
#pragma unroll
  for (int k8 = 0; k8 < 2; k8++) {
    float4 g[8];
#pragma unroll
    for (int u = 0; u < 8; u++) {
      int e4 = tid + 256 * (k8 * 8 + u);
      int i = e4 >> 5;
      int l4 = (e4 & 31) << 2;
      g[u] = *(const float4*)(G + (size_t)(rowA0 + i) * n + colB0 + l4);
    }
#pragma unroll
    for (int u = 0; u < 8; u++) {
      int e4 = tid + 256 * (k8 * 8 + u);
      int i = e4 >> 5;
      int l4 = (e4 & 31) << 2;
      float rih = 0.5f * Ri[i];
      int ma = maskA[i];
      float w0 = (ma && maskB[l4 + 0]) ? __expf(g[u].x - rih - 0.5f * Cl[l4 + 0]) : 0.0f;
      float w1 = (ma && maskB[l4 + 1]) ? __expf(g[u].y - rih - 0.5f * Cl[l4 + 1]) : 0.0f;
      float w2 = (ma && maskB[l4 + 2]) ? __expf(g[u].z - rih - 0.5f * Cl[l4 + 2]) : 0.0f;
      float w3 = (ma && maskB[l4 + 3]) ? __expf(g[u].w - rih - 0.5f * Cl[l4 + 3]) : 0.0f;
      uint2 packed;
      packed.x = (unsigned)f2bf(w0) | ((unsigned)f2bf(w1) << 16);
      packed.y = (unsigned)f2bf(w2) | ((unsigned)f2bf(w3) << 16);
      *(uint2*)&W[i][l4] = packed;
    }
  }

  // t_pos parallel gather (part 0 only): one latency round.
  if (part == 0) {
    int p = tid >> 4, q = tid & 15;
    float v = 0.0f;
    if (p < nP && q < nQ) v = G[(size_t)Plist[p] * n + Qlist[q]];
    SMRAW[p][q] = v;
  }
  __syncthreads();

  // SYRK: rows [part*16 .. +16) x 128 cols, K=128 bf16 from LDS.
  // All 8 B-reads issued into independent registers BEFORE any unpack/FMA.
  const int i0 = part * 16;
  const int ty = tid >> 4, tx = tid & 15;
  const float riA = Ri[i0 + ty];
  float acc[8];
#pragma unroll
  for (int c = 0; c < 8; c++) acc[c] = 0.0f;

  for (int kk = 0; kk < 128; kk += 8) {
    uint4 ar = *(const uint4*)&W[i0 + ty][kk];
    uint4 br[8];
#pragma unroll
    for (int c = 0; c < 8; c++) br[c] = *(const uint4*)&W[tx + 16 * c][kk];
    float a0 = BFLO(ar.x), a1 = BFHI(ar.x), a2 = BFLO(ar.y), a3 = BFHI(ar.y);
    float a4 = BFLO(ar.z), a5 = BFHI(ar.z), a6 = BFLO(ar.w), a7 = BFHI(ar.w);
#pragma unroll
    for (int c = 0; c < 8; c++) {
      acc[c] += a0 * BFLO(br[c].x) + a1 * BFHI(br[c].x) +
                a2 * BFLO(br[c].y) + a3 * BFHI(br[c].y) +
                a4 * BFLO(br[c].z) + a5 * BFHI(br[c].z) +
                a6 * BFLO(br[c].w) + a7 * BFHI(br[c].w);
    }
  }

  float lsum = 0.0f;
#pragma unroll
  for (int c = 0; c < 8; c++) {
    int j = tx + 16 * c;
    float t = __expf(0.5f * (Ri[j] - riA)) * acc[c];
    lsum += fmaxf(sqrtf(fmaxf(t, EPSF)) - 0.2f, 0.0f);
  }
  red[tid] = lsum;
  __syncthreads();
  for (int s2 = 128; s2 > 0; s2 >>= 1) {
    if (tid < s2) red[tid] += red[tid + s2];
    __syncthreads();
  }
  if (tid == 0) lsp[cls * 8 + part] = red[0];

  if (part == 0) {
    __syncthreads();
    red[tid] = (tid < 128) ? (float)maskA[tid] : 0.0f;
    __syncthreads();
    for (int s2 = 128; s2 > 0; s2 >>= 1) {
      if (tid < s2) red[tid] += red[tid + s2];
      __syncthreads();
    }
    if (tid == 0) { cnts[cls * 2 + 0] = red[0]; cnts[cls * 2 + 1] = (float)nP; }

    if (tid < nP) {
      float mx = -1e30f;
      for (int q = 0; q < nQ; q++) mx = fmaxf(mx, SMRAW[tid][q]);
      float s = 0.0f;
      for (int q = 0; q < nQ; q++) s += __expf(SMRAW[tid][q] - mx);
      for (int q = 0; q < nQ; q++) SP[tid][q] = __expf(SMRAW[tid][q] - mx) / s;
    }
    if (tid >= 64 && tid < 64 + nQ) {
      int q = tid - 64;
      float mx = -1e30f;
      for (int p = 0; p < nP; p++) mx = fmaxf(mx, SMRAW[p][q]);
      float s = 0.0f;
      for (int p = 0; p < nP; p++) s += __expf(SMRAW[p][q] - mx);
      for (int p = 0; p < nP; p++) SQ[q][p] = __expf(SMRAW[p][q] - mx) / s;
    }
    __syncthreads();
    float lv = 0.0f;
    if (tid < nP * nP) {
      int i = tid / nP, j = tid - i * nP;
      float t = 0.0f;
      for (int l = 0; l < nQ; l++) t += SP[i][l] * SQ[l][j];
      lv = fmaxf(0.5f - sqrtf(fmaxf(t, EPSF)), 0.0f);
    }
    red[tid] = lv;
    __syncthreads();
    for (int s2 = 128; s2 > 0; s2 >>= 1) {
      if (tid < s2) red[tid] += red[tid + s2];
      __syncthreads();
    }
    if (tid == 0) lan[cls] = red[0];
  }
}

__global__ void final_reduce(const float* __restrict__ lsp,
                             const float* __restrict__ lan,
                             const float* __restrict__ cnts,
                             const float* __restrict__ flags,
                             float* __restrict__ out, int n) {
  __shared__ float rl[256], rf[256];
  const int tid = threadIdx.x;
  float lv = 0.0f;
  if (tid < 64) {
    float nA = cnts[tid * 2 + 0];
    float nP = cnts[tid * 2 + 1];
    if (nP > 0.5f && nA > 0.5f) {
      float s = 0.0f;
      for (int p = 0; p < 8; p++) s += lsp[tid * 8 + p];
      float lc = s / (nA * nA) + lan[tid] / (nP * nP);
      lv = nP * lc;
    }
  }
  rl[tid] = lv;
  rf[tid] = flags[tid];
  __syncthreads();
  for (int s2 = 128; s2 > 0; s2 >>= 1) {
    if (tid < s2) { rl[tid] += rl[tid + s2]; rf[tid] += rf[tid + s2]; }
    __syncthreads();
  }
  if (tid == 0) {
    out[0] = rl[0] / (float)n;
    out[1] = rf[0];
  }
}

extern "C" void kernel_launch(void* const* d_in, const int* in_sizes, int n_in,
                              void* d_out, int out_size, void* d_ws,
                              size_t ws_size, hipStream_t stream) {
  const float* feature = (const float*)d_in[0];
  const int* targets = (const int*)d_in[1];
  const int n = in_sizes[1];            // 256
  const int d = in_sizes[0] / n;        // 2048
  const int nn = n * n;
  const size_t small = 512 + 64 + 128 + 256 + (size_t)n * 32;

  int S = 1;
  if (ws_size >= (small + nn + (size_t)16 * nn) * sizeof(float)) S = 16;
  else if (ws_size >= (small + nn + (size_t)4 * nn) * sizeof(float)) S = 4;

  float* ws = (float*)d_ws;
  float* lsp = ws;                 // 512
  float* lan = lsp + 512;          // 64
  float* cnts = lan + 64;          // 128
  float* flags = cnts + 128;       // 256
  float* LSEtab = flags + 256;     // n*32
  float* G = LSEtab + (size_t)n * 32;   // nn
  float* Gp = (S > 1) ? (G + nn) : G;
  float* out = (float*)d_out;

  dim3 gg(n / 64, n / 64, S);
  gemm_tile<<<gg, 256, 0, stream>>>(feature, Gp, n, d, d / S);
  if (S > 1)
    reduce_slices<<<(nn + 1023) / 1024, 256, 0, stream>>>(Gp, G, nn, S);

  stats_kernel<<<n / 4, 256, 0, stream>>>(G, targets, LSEtab, flags, n);

  dim3 gc(64, 8);
  TransitionLoss_30666066494151_kernel<<<gc, 256, 0, stream>>>(
      G, targets, LSEtab, lsp, lan, cnts, n);

  final_reduce<<<1, 256, 0, stream>>>(lsp, lan, cnts, flags, out, n);
}